// Round 3
// baseline (779.692 us; speedup 1.0000x reference)
//
#include <hip/hip_runtime.h>

// ---------------------------------------------------------------------------
// SubAttention fused pipeline for MI355X (gfx950). f32 I/O, bf16 MFMA compute.
// B=8 T=2048 Tc=512 D=1024 Dc=512 H=8 hd=128 N=2560
// ---------------------------------------------------------------------------

typedef short s16x8 __attribute__((ext_vector_type(8)));
typedef float f32x4 __attribute__((ext_vector_type(4)));

__device__ __forceinline__ float b2f(short s) {
    unsigned int u = ((unsigned int)(unsigned short)s) << 16;
    return __uint_as_float(u);
}
__device__ __forceinline__ short f2b(float f) {
    unsigned int u = __float_as_uint(f);
    u += 0x7fffu + ((u >> 16) & 1u);   // round-to-nearest-even
    return (short)(u >> 16);
}

typedef void __attribute__((address_space(1)))* gas_ptr;
typedef void __attribute__((address_space(3)))* las_ptr;
__device__ __forceinline__ void async_cp16(const void* g, void* l) {
    __builtin_amdgcn_global_load_lds((gas_ptr)g, (las_ptr)l, 16, 0, 0);
}

__device__ __forceinline__ float pen_of(const float* __restrict__ cmask,
                                        const float* __restrict__ smask,
                                        int b, int n) {
    float mk = (n < 512) ? cmask[b * 512 + n] : smask[b * 2048 + n - 512];
    return (1.0f - mk) * -1000000.0f;
}

// ---------------------------------------------------------------------------
// f32 -> bf16 conversion (weights). n divisible by 4.
__global__ __launch_bounds__(256) void cvt_kernel(const float* __restrict__ in,
                                                  short* __restrict__ out, int n) {
    int i = (blockIdx.x * 256 + threadIdx.x) * 4;
    if (i < n) {
        float4 v = *(const float4*)&in[i];
        short4 o;
        o.x = f2b(v.x); o.y = f2b(v.y); o.z = f2b(v.z); o.w = f2b(v.w);
        *(short4*)&out[i] = o;
    }
}

// ---------------------------------------------------------------------------
// LayerNorm: one row (length L = 1024 or 512) per block of 256 threads.
// f32 in, bf16 out.
__global__ __launch_bounds__(256) void ln_kernel(const float* __restrict__ x,
                                                 const float* __restrict__ g,
                                                 const float* __restrict__ be,
                                                 short* __restrict__ out, int L) {
    long row = blockIdx.x;
    const float* xr = x + row * L;
    short* orow = out + row * L;
    int tid = threadIdx.x;
    int i0 = tid * 4;
    bool active = i0 < L;
    float v0 = 0.f, v1 = 0.f, v2 = 0.f, v3 = 0.f;
    if (active) {
        float4 p = *(const float4*)&xr[i0];
        v0 = p.x; v1 = p.y; v2 = p.z; v3 = p.w;
    }
    float s = v0 + v1 + v2 + v3;
    float s2 = v0*v0 + v1*v1 + v2*v2 + v3*v3;
    #pragma unroll
    for (int off = 32; off > 0; off >>= 1) {
        s  += __shfl_down(s, off);
        s2 += __shfl_down(s2, off);
    }
    __shared__ float ss[4], sq[4];
    int wave = tid >> 6, lane = tid & 63;
    if (lane == 0) { ss[wave] = s; sq[wave] = s2; }
    __syncthreads();
    if (tid == 0) {
        float t1 = ss[0] + ss[1] + ss[2] + ss[3];
        float t2 = sq[0] + sq[1] + sq[2] + sq[3];
        float mu = t1 / (float)L;
        float var = t2 / (float)L - mu * mu;
        ss[0] = mu;
        sq[0] = rsqrtf(var + 1e-5f);
    }
    __syncthreads();
    float mu = ss[0], rs = sq[0];
    if (active) {
        float4 gp = *(const float4*)&g[i0];
        float4 bp = *(const float4*)&be[i0];
        short4 o;
        o.x = f2b((v0 - mu) * rs * gp.x + bp.x);
        o.y = f2b((v1 - mu) * rs * gp.y + bp.y);
        o.z = f2b((v2 - mu) * rs * gp.z + bp.z);
        o.w = f2b((v3 - mu) * rs * gp.w + bp.w);
        *(short4*)&orow[i0] = o;
    }
}

// ---------------------------------------------------------------------------
// q softmax over last axis (rows of 128 f32). 4 rows per block (1 wave each).
// bf16 out.
__global__ __launch_bounds__(256) void qsoftmax_kernel(const float* __restrict__ q,
                                                       short* __restrict__ out) {
    long row = (long)blockIdx.x * 4 + (threadIdx.x >> 6);
    int lane = threadIdx.x & 63;
    const float* qr = q + row * 128;
    float2 p = *(const float2*)&qr[lane * 2];
    float v0 = p.x, v1 = p.y;
    float m = fmaxf(v0, v1);
    #pragma unroll
    for (int off = 32; off > 0; off >>= 1) m = fmaxf(m, __shfl_xor(m, off));
    float e0 = __expf(v0 - m), e1 = __expf(v1 - m);
    float s = e0 + e1;
    #pragma unroll
    for (int off = 32; off > 0; off >>= 1) s += __shfl_xor(s, off);
    float inv = 1.0f / s;
    short2 o; o.x = f2b(e0 * inv); o.y = f2b(e1 * inv);
    *(short2*)&out[row * 128 + lane * 2] = o;
}

// ---------------------------------------------------------------------------
// Column-softmax stats over n (N=2560), coalesced: one channel per thread.
// Pass 1: grid (4 c-tiles, 8 b, 10 n-slices of 256). Partial (m,s) out.
__global__ __launch_bounds__(256) void kstats1(const short* __restrict__ klog,
                                               const float* __restrict__ cmask,
                                               const float* __restrict__ smask,
                                               float* __restrict__ partM,
                                               float* __restrict__ partS) {
    int c = blockIdx.x * 256 + threadIdx.x;
    int b = blockIdx.y;
    int n0 = blockIdx.z * 256;
    const short* base = klog + (long)b * 2560 * 1024 + c;
    float m = -3.4e38f, s = 0.f;
    for (int k = 0; k < 256; ++k) {
        int n = n0 + k;
        float v = b2f(base[(long)n * 1024]) + pen_of(cmask, smask, b, n);
        float nm = fmaxf(m, v);
        s = s * __expf(m - nm) + __expf(v - nm);
        m = nm;
    }
    long o = ((long)(b * 10 + blockIdx.z)) * 1024 + c;
    partM[o] = m;
    partS[o] = s;
}

// Pass 2: combine the 10 partials -> M and 1/S. grid (4, 8).
__global__ __launch_bounds__(256) void kstats2(const float* __restrict__ partM,
                                               const float* __restrict__ partS,
                                               float* __restrict__ Ms,
                                               float* __restrict__ iSs) {
    int c = blockIdx.x * 256 + threadIdx.x;
    int b = blockIdx.y;
    float M = -3.4e38f;
    #pragma unroll
    for (int k = 0; k < 10; ++k)
        M = fmaxf(M, partM[((long)(b * 10 + k)) * 1024 + c]);
    float S = 0.f;
    #pragma unroll
    for (int k = 0; k < 10; ++k) {
        long o = ((long)(b * 10 + k)) * 1024 + c;
        S += partS[o] * __expf(partM[o] - M);
    }
    Ms[b * 1024 + c] = M;
    iSs[b * 1024 + c] = 1.0f / S;
}

// ---------------------------------------------------------------------------
// Generic 128x128-tile bf16 MFMA B^T GEMM (m97 recipe): C = A(MxK) * B(NxK)^T
// MODE 1 (V)  : bf16 out = (acc + bias[n]) * mask[row]
// MODE 2 (Y)  : batched over z=(b,h); bf16 out = acc at col h*128+n
// MODE 3 (KLOG): bf16 out = acc + bias[n]
// MODE 4 (OUT): f32 out = acc + bias[n]
template<int MODE>
__global__ __launch_bounds__(256) void gemm_bt(
        const short* __restrict__ A, int lda, long strideA,
        const short* __restrict__ B, int ldb, long strideB,
        void* __restrict__ Out, int ldo, long strideO,
        int K,
        const float* __restrict__ bias,
        const float* __restrict__ mask, long strideMask) {
    __shared__ short As[128 * 64];
    __shared__ short Bs[128 * 64];
    int tid = threadIdx.x;
    int wave = tid >> 6, lane = tid & 63;
    int n0 = blockIdx.x * 128;
    int m0 = blockIdx.y * 128;
    int z = blockIdx.z;

    const short* Ab;
    const short* Bb;
    if (MODE == 2) {
        int b = z >> 3, h = z & 7;
        Ab = A + (long)b * strideA + h * 128;
        Bb = B + (long)z * 128 * 128;
    } else {
        Ab = A + (long)z * strideA;
        Bb = B + (long)z * strideB;
    }

    f32x4 acc[4][4];
    #pragma unroll
    for (int i = 0; i < 4; ++i)
        #pragma unroll
        for (int j = 0; j < 4; ++j) {
            f32x4 zz = {0.f, 0.f, 0.f, 0.f};
            acc[i][j] = zz;
        }

    int wm = wave >> 1, wn = wave & 1;
    int r = lane & 15, q = lane >> 4;

    for (int k0 = 0; k0 < K; k0 += 64) {
        __syncthreads();
        #pragma unroll
        for (int it = 0; it < 4; ++it) {
            int e = (it * 256 + tid) * 8;
            int row = e >> 6, kk = e & 63;
            const short* ga = Ab + (long)(m0 + row) * lda + k0 + kk;
            const short* gb = Bb + (long)(n0 + row) * ldb + k0 + kk;
            async_cp16(ga, &As[e]);
            async_cp16(gb, &Bs[e]);
        }
        __syncthreads();
        #pragma unroll
        for (int kk = 0; kk < 64; kk += 32) {
            s16x8 af[4], bfr[4];
            #pragma unroll
            for (int i = 0; i < 4; ++i) {
                af[i]  = *(const s16x8*)&As[(wm * 64 + i * 16 + r) * 64 + kk + q * 8];
                bfr[i] = *(const s16x8*)&Bs[(wn * 64 + i * 16 + r) * 64 + kk + q * 8];
            }
            #pragma unroll
            for (int i = 0; i < 4; ++i)
                #pragma unroll
                for (int j = 0; j < 4; ++j)
                    acc[i][j] = __builtin_amdgcn_mfma_f32_16x16x32_bf16(af[i], bfr[j], acc[i][j], 0, 0, 0);
        }
    }

    // Epilogue: C/D layout col = lane&15, row = (lane>>4)*4 + reg  [m89/m91]
    #pragma unroll
    for (int i = 0; i < 4; ++i) {
        int gmb = m0 + wm * 64 + i * 16 + q * 4;
        #pragma unroll
        for (int j = 0; j < 4; ++j) {
            int gn = n0 + wn * 64 + j * 16 + r;
            #pragma unroll
            for (int rg = 0; rg < 4; ++rg) {
                int row = gmb + rg;
                float v = acc[i][j][rg];
                if (MODE == 1) {
                    float bi = bias[gn];
                    float mk = mask[(long)z * strideMask + row];
                    ((short*)Out)[(long)z * strideO + (long)row * ldo + gn] =
                        f2b((v + bi) * mk);
                } else if (MODE == 2) {
                    int b = z >> 3, h = z & 7;
                    ((short*)Out)[(long)b * strideO + (long)row * ldo + h * 128 + gn] = f2b(v);
                } else if (MODE == 3) {
                    float bi = bias[gn];
                    ((short*)Out)[(long)z * strideO + (long)row * ldo + gn] = f2b(v + bi);
                } else {
                    float bi = bias[gn];
                    ((float*)Out)[(long)z * strideO + (long)row * ldo + gn] = v + bi;
                }
            }
        }
    }
}

// ---------------------------------------------------------------------------
// Fused column-softmax + linear-attention KV:
// attn[b,h][d][l] = sum_n softmax_n(klog+pen)[n,d] * v[n,l]; writes attnT[l][d].
// One block per (b,h); 64-n tiles staged transposed (exp applied in staging,
// 1/S folded into the d-row epilogue).
__global__ __launch_bounds__(256) void attn_fused(const short* __restrict__ klog,
                                                  const short* __restrict__ vbuf,
                                                  const float* __restrict__ cmask,
                                                  const float* __restrict__ smask,
                                                  const float* __restrict__ Ms,
                                                  const float* __restrict__ iSs,
                                                  short* __restrict__ attnT) {
    const int LDT = 72;  // padded n-stride
    __shared__ short kT[128 * LDT];
    __shared__ short vT[128 * LDT];
    int z = blockIdx.x;
    int b = z >> 3, h = z & 7;
    int tid = threadIdx.x;
    int wave = tid >> 6, lane = tid & 63;
    int r = lane & 15, q = lane >> 4;
    int wm = wave >> 1, wn = wave & 1;

    int cg = h * 128 + lane * 2;          // this lane's two global channels
    float M0 = Ms[b * 1024 + cg];
    float M1 = Ms[b * 1024 + cg + 1];

    f32x4 acc[4][4];
    #pragma unroll
    for (int i = 0; i < 4; ++i)
        #pragma unroll
        for (int j = 0; j < 4; ++j) {
            f32x4 zz = {0.f, 0.f, 0.f, 0.f};
            acc[i][j] = zz;
        }

    long base = ((long)b * 2560) * 1024 + h * 128;
    for (int n0 = 0; n0 < 2560; n0 += 64) {
        __syncthreads();
        #pragma unroll 4
        for (int i = 0; i < 16; ++i) {
            int nl = i * 4 + wave;
            int n = n0 + nl;
            float pen = pen_of(cmask, smask, b, n);
            long g = base + (long)n * 1024 + lane * 2;
            short2 k2 = *(const short2*)&klog[g];
            short2 v2 = *(const short2*)&vbuf[g];
            float w0 = __expf(b2f(k2.x) + pen - M0);
            float w1 = __expf(b2f(k2.y) + pen - M1);
            int c = lane * 2;
            kT[c * LDT + nl] = f2b(w0);
            kT[(c + 1) * LDT + nl] = f2b(w1);
            vT[c * LDT + nl] = v2.x;
            vT[(c + 1) * LDT + nl] = v2.y;
        }
        __syncthreads();
        #pragma unroll
        for (int kk = 0; kk < 64; kk += 32) {
            s16x8 af[4], bfr[4];
            #pragma unroll
            for (int i = 0; i < 4; ++i) {
                af[i]  = *(const s16x8*)&kT[(wm * 64 + i * 16 + r) * LDT + kk + q * 8];
                bfr[i] = *(const s16x8*)&vT[(wn * 64 + i * 16 + r) * LDT + kk + q * 8];
            }
            #pragma unroll
            for (int i = 0; i < 4; ++i)
                #pragma unroll
                for (int j = 0; j < 4; ++j)
                    acc[i][j] = __builtin_amdgcn_mfma_f32_16x16x32_bf16(af[i], bfr[j], acc[i][j], 0, 0, 0);
        }
    }
    short* outz = attnT + (long)z * 16384;
    #pragma unroll
    for (int i = 0; i < 4; ++i)
        #pragma unroll
        for (int j = 0; j < 4; ++j)
            #pragma unroll
            for (int rg = 0; rg < 4; ++rg) {
                int d = wm * 64 + i * 16 + q * 4 + rg;
                int l = wn * 64 + j * 16 + r;
                float iS = iSs[b * 1024 + h * 128 + d];
                outz[l * 128 + d] = f2b(acc[i][j][rg] * iS);
            }
}

// ---------------------------------------------------------------------------
extern "C" void kernel_launch(void* const* d_in, const int* in_sizes, int n_in,
                              void* d_out, int out_size, void* d_ws, size_t ws_size,
                              hipStream_t stream) {
    const float* query = (const float*)d_in[0];
    const float* x     = (const float*)d_in[1];
    const float* cond  = (const float*)d_in[2];
    const float* smask = (const float*)d_in[3];
    const float* cmask = (const float*)d_in[4];
    const float* gx  = (const float*)d_in[5];
    const float* bx  = (const float*)d_in[6];
    const float* gc  = (const float*)d_in[7];
    const float* bc  = (const float*)d_in[8];
    const float* Wkc = (const float*)d_in[9];
    const float* bkc = (const float*)d_in[10];
    const float* Wvc = (const float*)d_in[11];
    const float* bvc = (const float*)d_in[12];
    const float* Wkx = (const float*)d_in[13];
    const float* bkx = (const float*)d_in[14];
    const float* Wvx = (const float*)d_in[15];
    const float* bvx = (const float*)d_in[16];
    const float* Wy  = (const float*)d_in[17];
    const float* by  = (const float*)d_in[18];

    // Workspace layout (bytes):
    size_t o_xn    = 0;                      // 16384x1024 bf16 = 33,554,432
    size_t o_cn    = o_xn    + 33554432;     //  4096x512  bf16 =  4,194,304
    size_t o_klog  = o_cn    + 4194304;      // 8x2560x1024 bf16 = 41,943,040 (ybuf aliases)
    size_t o_vbuf  = o_klog  + 41943040;     // 8x2560x1024 bf16 = 41,943,040
    size_t o_qsm   = o_vbuf  + 41943040;     // 16384x1024 bf16 = 33,554,432
    size_t o_attnT = o_qsm   + 33554432;     // 64x128x128 bf16 =  2,097,152
    size_t o_partM = o_attnT + 2097152;      // 8x10x1024 f32   =    327,680
    size_t o_partS = o_partM + 327680;
    size_t o_Ms    = o_partS + 327680;       // 8x1024 f32      =     32,768
    size_t o_iSs   = o_Ms    + 32768;
    size_t o_wkc   = o_iSs   + 32768;        // 1024x512 bf16   =  1,048,576
    size_t o_wvc   = o_wkc   + 1048576;
    size_t o_wkx   = o_wvc   + 1048576;      // 1024x1024 bf16  =  2,097,152
    size_t o_wvx   = o_wkx   + 2097152;
    size_t o_wy    = o_wvx   + 2097152;
    size_t need    = o_wy    + 2097152;      // = 166,395,904
    if (ws_size < need) return;  // clean no-op -> diagnosable absmax failure

    char* w = (char*)d_ws;
    short* xn    = (short*)(w + o_xn);
    short* cn    = (short*)(w + o_cn);
    short* klog  = (short*)(w + o_klog);
    short* vbuf  = (short*)(w + o_vbuf);
    short* qsm   = (short*)(w + o_qsm);
    short* attnT = (short*)(w + o_attnT);
    float* partM = (float*)(w + o_partM);
    float* partS = (float*)(w + o_partS);
    float* Ms    = (float*)(w + o_Ms);
    float* iSs   = (float*)(w + o_iSs);
    short* wkc   = (short*)(w + o_wkc);
    short* wvc   = (short*)(w + o_wvc);
    short* wkx   = (short*)(w + o_wkx);
    short* wvx   = (short*)(w + o_wvx);
    short* wy    = (short*)(w + o_wy);
    short* ybuf  = klog;  // klog dead after attn_fused

    // Weight conversion f32 -> bf16
    cvt_kernel<<<512, 256, 0, stream>>>(Wkc, wkc, 524288);
    cvt_kernel<<<512, 256, 0, stream>>>(Wvc, wvc, 524288);
    cvt_kernel<<<1024, 256, 0, stream>>>(Wkx, wkx, 1048576);
    cvt_kernel<<<1024, 256, 0, stream>>>(Wvx, wvx, 1048576);
    cvt_kernel<<<1024, 256, 0, stream>>>(Wy, wy, 1048576);

    ln_kernel<<<16384, 256, 0, stream>>>(x, gx, bx, xn, 1024);
    ln_kernel<<<4096, 256, 0, stream>>>(cond, gc, bc, cn, 512);
    qsoftmax_kernel<<<32768, 256, 0, stream>>>(query, qsm);

    // k logits (k + bias, bf16; penalty applied by consumers in f32)
    gemm_bt<3><<<dim3(8, 16, 8), 256, 0, stream>>>(
        xn, 1024, 2097152L, wkx, 1024, 0L,
        klog + 512 * 1024, 1024, 2621440L,
        1024, bkx, nullptr, 0L);
    gemm_bt<3><<<dim3(8, 4, 8), 256, 0, stream>>>(
        cn, 512, 262144L, wkc, 512, 0L,
        klog, 1024, 2621440L,
        512, bkc, nullptr, 0L);
    // v (masked)
    gemm_bt<1><<<dim3(8, 16, 8), 256, 0, stream>>>(
        xn, 1024, 2097152L, wvx, 1024, 0L,
        vbuf + 512 * 1024, 1024, 2621440L,
        1024, bvx, smask, 2048L);
    gemm_bt<1><<<dim3(8, 4, 8), 256, 0, stream>>>(
        cn, 512, 262144L, wvc, 512, 0L,
        vbuf, 1024, 2621440L,
        512, bvc, cmask, 512L);

    kstats1<<<dim3(4, 8, 10), 256, 0, stream>>>(klog, cmask, smask, partM, partS);
    kstats2<<<dim3(4, 8), 256, 0, stream>>>(partM, partS, Ms, iSs);

    attn_fused<<<64, 256, 0, stream>>>(klog, vbuf, cmask, smask, Ms, iSs, attnT);

    // y[b,t,h*128+l] = q_sm[b,t,h,:] @ attnT[b,h][l,:]
    gemm_bt<2><<<dim3(1, 16, 64), 256, 0, stream>>>(
        qsm, 1024, 2097152L, attnT, 128, 16384L,
        ybuf, 1024, 2097152L,
        128, nullptr, nullptr, 0L);
    // out = y @ W_y^T + b_y  (f32 out)
    gemm_bt<4><<<dim3(8, 128, 1), 256, 0, stream>>>(
        ybuf, 1024, 0L, wy, 1024, 0L,
        d_out, 1024, 0L,
        1024, by, nullptr, 0L);
}

// Round 4
// 531.183 us; speedup vs baseline: 1.4678x; 1.4678x over previous
//
#include <hip/hip_runtime.h>

// ---------------------------------------------------------------------------
// SubAttention fused pipeline for MI355X (gfx950). f32 I/O, bf16 MFMA compute.
// B=8 T=2048 Tc=512 D=1024 Dc=512 H=8 hd=128 N=2560
// ---------------------------------------------------------------------------

typedef short s16x8 __attribute__((ext_vector_type(8)));
typedef float f32x4 __attribute__((ext_vector_type(4)));

__device__ __forceinline__ float b2f(short s) {
    unsigned int u = ((unsigned int)(unsigned short)s) << 16;
    return __uint_as_float(u);
}
__device__ __forceinline__ short f2b(float f) {
    unsigned int u = __float_as_uint(f);
    u += 0x7fffu + ((u >> 16) & 1u);   // round-to-nearest-even
    return (short)(u >> 16);
}

typedef void __attribute__((address_space(1)))* gas_ptr;
typedef void __attribute__((address_space(3)))* las_ptr;
__device__ __forceinline__ void async_cp16(const void* g, void* l) {
    __builtin_amdgcn_global_load_lds((gas_ptr)g, (las_ptr)l, 16, 0, 0);
}

__device__ __forceinline__ float pen_of(const float* __restrict__ cmask,
                                        const float* __restrict__ smask,
                                        int b, int n) {
    float mk = (n < 512) ? cmask[b * 512 + n] : smask[b * 2048 + n - 512];
    return (1.0f - mk) * -1000000.0f;
}

// ---------------------------------------------------------------------------
// f32 -> bf16 conversion (weights). n divisible by 4.
__global__ __launch_bounds__(256) void cvt_kernel(const float* __restrict__ in,
                                                  short* __restrict__ out, int n) {
    int i = (blockIdx.x * 256 + threadIdx.x) * 4;
    if (i < n) {
        float4 v = *(const float4*)&in[i];
        short4 o;
        o.x = f2b(v.x); o.y = f2b(v.y); o.z = f2b(v.z); o.w = f2b(v.w);
        *(short4*)&out[i] = o;
    }
}

// ---------------------------------------------------------------------------
// LayerNorm: one row (length L = 1024 or 512) per block of 256 threads.
// f32 in, bf16 out.
__global__ __launch_bounds__(256) void ln_kernel(const float* __restrict__ x,
                                                 const float* __restrict__ g,
                                                 const float* __restrict__ be,
                                                 short* __restrict__ out, int L) {
    long row = blockIdx.x;
    const float* xr = x + row * L;
    short* orow = out + row * L;
    int tid = threadIdx.x;
    int i0 = tid * 4;
    bool active = i0 < L;
    float v0 = 0.f, v1 = 0.f, v2 = 0.f, v3 = 0.f;
    if (active) {
        float4 p = *(const float4*)&xr[i0];
        v0 = p.x; v1 = p.y; v2 = p.z; v3 = p.w;
    }
    float s = v0 + v1 + v2 + v3;
    float s2 = v0*v0 + v1*v1 + v2*v2 + v3*v3;
    #pragma unroll
    for (int off = 32; off > 0; off >>= 1) {
        s  += __shfl_down(s, off);
        s2 += __shfl_down(s2, off);
    }
    __shared__ float ss[4], sq[4];
    int wave = tid >> 6, lane = tid & 63;
    if (lane == 0) { ss[wave] = s; sq[wave] = s2; }
    __syncthreads();
    if (tid == 0) {
        float t1 = ss[0] + ss[1] + ss[2] + ss[3];
        float t2 = sq[0] + sq[1] + sq[2] + sq[3];
        float mu = t1 / (float)L;
        float var = t2 / (float)L - mu * mu;
        ss[0] = mu;
        sq[0] = rsqrtf(var + 1e-5f);
    }
    __syncthreads();
    float mu = ss[0], rs = sq[0];
    if (active) {
        float4 gp = *(const float4*)&g[i0];
        float4 bp = *(const float4*)&be[i0];
        short4 o;
        o.x = f2b((v0 - mu) * rs * gp.x + bp.x);
        o.y = f2b((v1 - mu) * rs * gp.y + bp.y);
        o.z = f2b((v2 - mu) * rs * gp.z + bp.z);
        o.w = f2b((v3 - mu) * rs * gp.w + bp.w);
        *(short4*)&orow[i0] = o;
    }
}

// ---------------------------------------------------------------------------
// q softmax over last axis (rows of 128 f32). 4 rows per block (1 wave each).
// bf16 out.
__global__ __launch_bounds__(256) void qsoftmax_kernel(const float* __restrict__ q,
                                                       short* __restrict__ out) {
    long row = (long)blockIdx.x * 4 + (threadIdx.x >> 6);
    int lane = threadIdx.x & 63;
    const float* qr = q + row * 128;
    float2 p = *(const float2*)&qr[lane * 2];
    float v0 = p.x, v1 = p.y;
    float m = fmaxf(v0, v1);
    #pragma unroll
    for (int off = 32; off > 0; off >>= 1) m = fmaxf(m, __shfl_xor(m, off));
    float e0 = __expf(v0 - m), e1 = __expf(v1 - m);
    float s = e0 + e1;
    #pragma unroll
    for (int off = 32; off > 0; off >>= 1) s += __shfl_xor(s, off);
    float inv = 1.0f / s;
    short2 o; o.x = f2b(e0 * inv); o.y = f2b(e1 * inv);
    *(short2*)&out[row * 128 + lane * 2] = o;
}

// ---------------------------------------------------------------------------
// Column-softmax stats over n (N=2560), coalesced: one channel per thread.
// Pass 1: grid (4 c-tiles, 8 b, 10 n-slices of 256). Partial (m,s) out.
__global__ __launch_bounds__(256) void kstats1(const short* __restrict__ klog,
                                               const float* __restrict__ cmask,
                                               const float* __restrict__ smask,
                                               float* __restrict__ partM,
                                               float* __restrict__ partS) {
    int c = blockIdx.x * 256 + threadIdx.x;
    int b = blockIdx.y;
    int n0 = blockIdx.z * 256;
    const short* base = klog + (long)b * 2560 * 1024 + c;
    float m = -3.4e38f, s = 0.f;
    for (int k = 0; k < 256; ++k) {
        int n = n0 + k;
        float v = b2f(base[(long)n * 1024]) + pen_of(cmask, smask, b, n);
        float nm = fmaxf(m, v);
        s = s * __expf(m - nm) + __expf(v - nm);
        m = nm;
    }
    long o = ((long)(b * 10 + blockIdx.z)) * 1024 + c;
    partM[o] = m;
    partS[o] = s;
}

// Pass 2: combine the 10 partials -> M and 1/S. grid (4, 8).
__global__ __launch_bounds__(256) void kstats2(const float* __restrict__ partM,
                                               const float* __restrict__ partS,
                                               float* __restrict__ Ms,
                                               float* __restrict__ iSs) {
    int c = blockIdx.x * 256 + threadIdx.x;
    int b = blockIdx.y;
    float M = -3.4e38f;
    #pragma unroll
    for (int k = 0; k < 10; ++k)
        M = fmaxf(M, partM[((long)(b * 10 + k)) * 1024 + c]);
    float S = 0.f;
    #pragma unroll
    for (int k = 0; k < 10; ++k) {
        long o = ((long)(b * 10 + k)) * 1024 + c;
        S += partS[o] * __expf(partM[o] - M);
    }
    Ms[b * 1024 + c] = M;
    iSs[b * 1024 + c] = 1.0f / S;
}

// ---------------------------------------------------------------------------
// Generic 128x128-tile bf16 MFMA B^T GEMM (m97 recipe): C = A(MxK) * B(NxK)^T
// MODE 1 (V)  : bf16 out = (acc + bias[n]) * mask[row]
// MODE 2 (Y)  : batched over z=(b,h); bf16 out = acc at col h*128+n
// MODE 3 (KLOG): bf16 out = acc + bias[n]
// MODE 4 (OUT): f32 out = acc + bias[n]
template<int MODE>
__global__ __launch_bounds__(256) void gemm_bt(
        const short* __restrict__ A, int lda, long strideA,
        const short* __restrict__ B, int ldb, long strideB,
        void* __restrict__ Out, int ldo, long strideO,
        int K,
        const float* __restrict__ bias,
        const float* __restrict__ mask, long strideMask) {
    __shared__ short As[128 * 64];
    __shared__ short Bs[128 * 64];
    int tid = threadIdx.x;
    int wave = tid >> 6, lane = tid & 63;
    int n0 = blockIdx.x * 128;
    int m0 = blockIdx.y * 128;
    int z = blockIdx.z;

    const short* Ab;
    const short* Bb;
    if (MODE == 2) {
        int b = z >> 3, h = z & 7;
        Ab = A + (long)b * strideA + h * 128;
        Bb = B + (long)z * 128 * 128;
    } else {
        Ab = A + (long)z * strideA;
        Bb = B + (long)z * strideB;
    }

    f32x4 acc[4][4];
    #pragma unroll
    for (int i = 0; i < 4; ++i)
        #pragma unroll
        for (int j = 0; j < 4; ++j) {
            f32x4 zz = {0.f, 0.f, 0.f, 0.f};
            acc[i][j] = zz;
        }

    int wm = wave >> 1, wn = wave & 1;
    int r = lane & 15, q = lane >> 4;

    for (int k0 = 0; k0 < K; k0 += 64) {
        __syncthreads();
        #pragma unroll
        for (int it = 0; it < 4; ++it) {
            int e = (it * 256 + tid) * 8;
            int row = e >> 6, kk = e & 63;
            const short* ga = Ab + (long)(m0 + row) * lda + k0 + kk;
            const short* gb = Bb + (long)(n0 + row) * ldb + k0 + kk;
            async_cp16(ga, &As[e]);
            async_cp16(gb, &Bs[e]);
        }
        __syncthreads();
        #pragma unroll
        for (int kk = 0; kk < 64; kk += 32) {
            s16x8 af[4], bfr[4];
            #pragma unroll
            for (int i = 0; i < 4; ++i) {
                af[i]  = *(const s16x8*)&As[(wm * 64 + i * 16 + r) * 64 + kk + q * 8];
                bfr[i] = *(const s16x8*)&Bs[(wn * 64 + i * 16 + r) * 64 + kk + q * 8];
            }
            #pragma unroll
            for (int i = 0; i < 4; ++i)
                #pragma unroll
                for (int j = 0; j < 4; ++j)
                    acc[i][j] = __builtin_amdgcn_mfma_f32_16x16x32_bf16(af[i], bfr[j], acc[i][j], 0, 0, 0);
        }
    }

    // Epilogue: C/D layout col = lane&15, row = (lane>>4)*4 + reg  [m89/m91]
    #pragma unroll
    for (int i = 0; i < 4; ++i) {
        int gmb = m0 + wm * 64 + i * 16 + q * 4;
        #pragma unroll
        for (int j = 0; j < 4; ++j) {
            int gn = n0 + wn * 64 + j * 16 + r;
            #pragma unroll
            for (int rg = 0; rg < 4; ++rg) {
                int row = gmb + rg;
                float v = acc[i][j][rg];
                if (MODE == 1) {
                    float bi = bias[gn];
                    float mk = mask[(long)z * strideMask + row];
                    ((short*)Out)[(long)z * strideO + (long)row * ldo + gn] =
                        f2b((v + bi) * mk);
                } else if (MODE == 2) {
                    int b = z >> 3, h = z & 7;
                    ((short*)Out)[(long)b * strideO + (long)row * ldo + h * 128 + gn] = f2b(v);
                } else if (MODE == 3) {
                    float bi = bias[gn];
                    ((short*)Out)[(long)z * strideO + (long)row * ldo + gn] = f2b(v + bi);
                } else {
                    float bi = bias[gn];
                    ((float*)Out)[(long)z * strideO + (long)row * ldo + gn] = v + bi;
                }
            }
        }
    }
}

// ---------------------------------------------------------------------------
// Split-K fused column-softmax + linear-attention KV partial:
// pbuf[z,ns][l][d] = sum_{n in slice ns} exp(klog+pen-M)[n,d] * v[n,l]  (f32)
// grid (NS=8, 64). Transposed LDS tile with XOR swizzle:
//   element (c, nl) stored at short index c*64 + (nl ^ (((c>>1)&7)<<3)).
__global__ __launch_bounds__(256) void attn_part(const short* __restrict__ klog,
                                                 const short* __restrict__ vbuf,
                                                 const float* __restrict__ cmask,
                                                 const float* __restrict__ smask,
                                                 const float* __restrict__ Ms,
                                                 float* __restrict__ pbuf) {
    __shared__ short kT[128 * 64];
    __shared__ short vT[128 * 64];
    int ns = blockIdx.x;
    int z = blockIdx.y;
    int b = z >> 3, h = z & 7;
    int tid = threadIdx.x;
    int wave = tid >> 6, lane = tid & 63;
    int r = lane & 15, q = lane >> 4;
    int wm = wave >> 1, wn = wave & 1;

    int cg = h * 128 + lane * 2;          // this lane's two global channels
    float M0 = Ms[b * 1024 + cg];
    float M1 = Ms[b * 1024 + cg + 1];

    f32x4 acc[4][4];
    #pragma unroll
    for (int i = 0; i < 4; ++i)
        #pragma unroll
        for (int j = 0; j < 4; ++j) {
            f32x4 zz = {0.f, 0.f, 0.f, 0.f};
            acc[i][j] = zz;
        }

    long base = ((long)b * 2560) * 1024 + h * 128;
    int nbase = ns * 320;
    int swz = (lane & 7) << 3;            // == ((c>>1)&7)<<3 for c=2*lane(,+1)
    for (int n0 = 0; n0 < 320; n0 += 64) {
        __syncthreads();
        #pragma unroll 4
        for (int i = 0; i < 16; ++i) {
            int nl = i * 4 + wave;
            int n = nbase + n0 + nl;
            float pen = pen_of(cmask, smask, b, n);
            long g = base + (long)n * 1024 + lane * 2;
            short2 k2 = *(const short2*)&klog[g];
            short2 v2 = *(const short2*)&vbuf[g];
            float w0 = __expf(b2f(k2.x) + pen - M0);
            float w1 = __expf(b2f(k2.y) + pen - M1);
            int c = lane * 2;
            int sw = nl ^ swz;
            kT[c * 64 + sw] = f2b(w0);
            kT[(c + 1) * 64 + sw] = f2b(w1);
            vT[c * 64 + sw] = v2.x;
            vT[(c + 1) * 64 + sw] = v2.y;
        }
        __syncthreads();
        #pragma unroll
        for (int kk = 0; kk < 64; kk += 32) {
            s16x8 af[4], bfr[4];
            #pragma unroll
            for (int i = 0; i < 4; ++i) {
                int cA = wm * 64 + i * 16 + r;
                int cB = wn * 64 + i * 16 + r;
                af[i]  = *(const s16x8*)&kT[cA * 64 + ((kk + q * 8) ^ (((cA >> 1) & 7) << 3))];
                bfr[i] = *(const s16x8*)&vT[cB * 64 + ((kk + q * 8) ^ (((cB >> 1) & 7) << 3))];
            }
            #pragma unroll
            for (int i = 0; i < 4; ++i)
                #pragma unroll
                for (int j = 0; j < 4; ++j)
                    acc[i][j] = __builtin_amdgcn_mfma_f32_16x16x32_bf16(af[i], bfr[j], acc[i][j], 0, 0, 0);
        }
    }
    // Partial write (f32): row l = wn*64+j*16+r, cols d = wm*64+i*16+q*4 .. +3
    float* outp = pbuf + ((long)z * 8 + ns) * 16384;
    #pragma unroll
    for (int i = 0; i < 4; ++i) {
        int d0 = wm * 64 + i * 16 + q * 4;
        #pragma unroll
        for (int j = 0; j < 4; ++j) {
            int l = wn * 64 + j * 16 + r;
            *(f32x4*)&outp[l * 128 + d0] = acc[i][j];
        }
    }
}

// Sum the 8 partials, apply 1/S (per d), emit bf16 attnT[z][l][d].
__global__ __launch_bounds__(256) void reduce_attn(const float* __restrict__ pbuf,
                                                   const float* __restrict__ iSs,
                                                   short* __restrict__ attnT) {
    int idx = blockIdx.x * 256 + threadIdx.x;   // over 64*16384
    int z = idx >> 14, rem = idx & 16383;
    int d = rem & 127;
    int b = z >> 3, h = z & 7;
    const float* p = pbuf + (long)z * 8 * 16384 + rem;
    float s = 0.f;
    #pragma unroll
    for (int ns = 0; ns < 8; ++ns) s += p[ns * 16384];
    attnT[idx] = f2b(s * iSs[b * 1024 + h * 128 + d]);
}

// ---------------------------------------------------------------------------
extern "C" void kernel_launch(void* const* d_in, const int* in_sizes, int n_in,
                              void* d_out, int out_size, void* d_ws, size_t ws_size,
                              hipStream_t stream) {
    const float* query = (const float*)d_in[0];
    const float* x     = (const float*)d_in[1];
    const float* cond  = (const float*)d_in[2];
    const float* smask = (const float*)d_in[3];
    const float* cmask = (const float*)d_in[4];
    const float* gx  = (const float*)d_in[5];
    const float* bx  = (const float*)d_in[6];
    const float* gc  = (const float*)d_in[7];
    const float* bc  = (const float*)d_in[8];
    const float* Wkc = (const float*)d_in[9];
    const float* bkc = (const float*)d_in[10];
    const float* Wvc = (const float*)d_in[11];
    const float* bvc = (const float*)d_in[12];
    const float* Wkx = (const float*)d_in[13];
    const float* bkx = (const float*)d_in[14];
    const float* Wvx = (const float*)d_in[15];
    const float* bvx = (const float*)d_in[16];
    const float* Wy  = (const float*)d_in[17];
    const float* by  = (const float*)d_in[18];

    // Workspace layout (bytes): (need unchanged from the passing r3 run)
    size_t o_xn    = 0;                      // 16384x1024 bf16 = 33,554,432 (pbuf aliases)
    size_t o_cn    = o_xn    + 33554432;     //  4096x512  bf16 =  4,194,304
    size_t o_klog  = o_cn    + 4194304;      // 8x2560x1024 bf16 = 41,943,040 (ybuf aliases)
    size_t o_vbuf  = o_klog  + 41943040;     // 8x2560x1024 bf16 = 41,943,040
    size_t o_qsm   = o_vbuf  + 41943040;     // 16384x1024 bf16 = 33,554,432
    size_t o_attnT = o_qsm   + 33554432;     // 64x128x128 bf16 =  2,097,152
    size_t o_partM = o_attnT + 2097152;      // 8x10x1024 f32   =    327,680
    size_t o_partS = o_partM + 327680;
    size_t o_Ms    = o_partS + 327680;       // 8x1024 f32      =     32,768
    size_t o_iSs   = o_Ms    + 32768;
    size_t o_wkc   = o_iSs   + 32768;        // 1024x512 bf16   =  1,048,576
    size_t o_wvc   = o_wkc   + 1048576;
    size_t o_wkx   = o_wvc   + 1048576;      // 1024x1024 bf16  =  2,097,152
    size_t o_wvx   = o_wkx   + 2097152;
    size_t o_wy    = o_wvx   + 2097152;
    size_t need    = o_wy    + 2097152;      // = 166,395,904
    if (ws_size < need) return;  // clean no-op -> diagnosable absmax failure

    char* w = (char*)d_ws;
    short* xn    = (short*)(w + o_xn);
    short* cn    = (short*)(w + o_cn);
    short* klog  = (short*)(w + o_klog);
    short* vbuf  = (short*)(w + o_vbuf);
    short* qsm   = (short*)(w + o_qsm);
    short* attnT = (short*)(w + o_attnT);
    float* partM = (float*)(w + o_partM);
    float* partS = (float*)(w + o_partS);
    float* Ms    = (float*)(w + o_Ms);
    float* iSs   = (float*)(w + o_iSs);
    short* wkc   = (short*)(w + o_wkc);
    short* wvc   = (short*)(w + o_wvc);
    short* wkx   = (short*)(w + o_wkx);
    short* wvx   = (short*)(w + o_wvx);
    short* wy    = (short*)(w + o_wy);
    short* ybuf  = klog;                 // klog dead after attn_part
    float* pbuf  = (float*)xn;           // xn dead after k/v GEMMs; 8*64*16384*4 = 33,554,432

    // Weight conversion f32 -> bf16
    cvt_kernel<<<512, 256, 0, stream>>>(Wkc, wkc, 524288);
    cvt_kernel<<<512, 256, 0, stream>>>(Wvc, wvc, 524288);
    cvt_kernel<<<1024, 256, 0, stream>>>(Wkx, wkx, 1048576);
    cvt_kernel<<<1024, 256, 0, stream>>>(Wvx, wvx, 1048576);
    cvt_kernel<<<1024, 256, 0, stream>>>(Wy, wy, 1048576);

    ln_kernel<<<16384, 256, 0, stream>>>(x, gx, bx, xn, 1024);
    ln_kernel<<<4096, 256, 0, stream>>>(cond, gc, bc, cn, 512);
    qsoftmax_kernel<<<32768, 256, 0, stream>>>(query, qsm);

    // k logits (k + bias, bf16; penalty applied by consumers in f32)
    gemm_bt<3><<<dim3(8, 16, 8), 256, 0, stream>>>(
        xn, 1024, 2097152L, wkx, 1024, 0L,
        klog + 512 * 1024, 1024, 2621440L,
        1024, bkx, nullptr, 0L);
    gemm_bt<3><<<dim3(8, 4, 8), 256, 0, stream>>>(
        cn, 512, 262144L, wkc, 512, 0L,
        klog, 1024, 2621440L,
        512, bkc, nullptr, 0L);
    // v (masked)
    gemm_bt<1><<<dim3(8, 16, 8), 256, 0, stream>>>(
        xn, 1024, 2097152L, wvx, 1024, 0L,
        vbuf + 512 * 1024, 1024, 2621440L,
        1024, bvx, smask, 2048L);
    gemm_bt<1><<<dim3(8, 4, 8), 256, 0, stream>>>(
        cn, 512, 262144L, wvc, 512, 0L,
        vbuf, 1024, 2621440L,
        512, bvc, cmask, 512L);

    kstats1<<<dim3(4, 8, 10), 256, 0, stream>>>(klog, cmask, smask, partM, partS);
    kstats2<<<dim3(4, 8), 256, 0, stream>>>(partM, partS, Ms, iSs);

    // Split-K attention KV (pbuf overwrites xn region — xn dead by now)
    attn_part<<<dim3(8, 64), 256, 0, stream>>>(klog, vbuf, cmask, smask, Ms, pbuf);
    reduce_attn<<<4096, 256, 0, stream>>>(pbuf, iSs, attnT);

    // y[b,t,h*128+l] = q_sm[b,t,h,:] @ attnT[b,h][l,:]
    gemm_bt<2><<<dim3(1, 16, 64), 256, 0, stream>>>(
        qsm, 1024, 2097152L, attnT, 128, 16384L,
        ybuf, 1024, 2097152L,
        128, nullptr, nullptr, 0L);
    // out = y @ W_y^T + b_y  (f32 out)
    gemm_bt<4><<<dim3(8, 128, 1), 256, 0, stream>>>(
        ybuf, 1024, 0L, wy, 1024, 0L,
        d_out, 1024, 0L,
        1024, by, nullptr, 0L);
}

// Round 5
// 528.546 us; speedup vs baseline: 1.4752x; 1.0050x over previous
//
#include <hip/hip_runtime.h>

// ---------------------------------------------------------------------------
// SubAttention fused pipeline for MI355X (gfx950). f32 I/O, bf16 MFMA compute.
// B=8 T=2048 Tc=512 D=1024 Dc=512 H=8 hd=128 N=2560
// ---------------------------------------------------------------------------

typedef short s16x8 __attribute__((ext_vector_type(8)));
typedef float f32x4 __attribute__((ext_vector_type(4)));

__device__ __forceinline__ float b2f(short s) {
    unsigned int u = ((unsigned int)(unsigned short)s) << 16;
    return __uint_as_float(u);
}
__device__ __forceinline__ short f2b(float f) {
    unsigned int u = __float_as_uint(f);
    u += 0x7fffu + ((u >> 16) & 1u);   // round-to-nearest-even
    return (short)(u >> 16);
}

typedef void __attribute__((address_space(1)))* gas_ptr;
typedef void __attribute__((address_space(3)))* las_ptr;
__device__ __forceinline__ void async_cp16(const void* g, void* l) {
    __builtin_amdgcn_global_load_lds((gas_ptr)g, (las_ptr)l, 16, 0, 0);
}

__device__ __forceinline__ float pen_of(const float* __restrict__ cmask,
                                        const float* __restrict__ smask,
                                        int b, int n) {
    float mk = (n < 512) ? cmask[b * 512 + n] : smask[b * 2048 + n - 512];
    return (1.0f - mk) * -1000000.0f;
}

// ---------------------------------------------------------------------------
// One-shot f32->bf16 weight conversion into the contiguous ws weight region:
// [wkc 512K][wvc 512K][wkx 1M][wvx 1M][wy 1M] elements.
__global__ __launch_bounds__(256) void cvt_all(const float* __restrict__ Wkc,
                                               const float* __restrict__ Wvc,
                                               const float* __restrict__ Wkx,
                                               const float* __restrict__ Wvx,
                                               const float* __restrict__ Wy,
                                               short* __restrict__ dst) {
    int g = (blockIdx.x * 256 + threadIdx.x) * 4;     // 0 .. 4194300
    const float* src;
    if (g < 524288)        src = Wkc + g;
    else if (g < 1048576)  src = Wvc + (g - 524288);
    else if (g < 2097152)  src = Wkx + (g - 1048576);
    else if (g < 3145728)  src = Wvx + (g - 2097152);
    else                   src = Wy  + (g - 3145728);
    float4 v = *(const float4*)src;
    short4 o;
    o.x = f2b(v.x); o.y = f2b(v.y); o.z = f2b(v.z); o.w = f2b(v.w);
    *(short4*)&dst[g] = o;
}

// ---------------------------------------------------------------------------
// LayerNorm: one row (length L = 1024 or 512) per block of 256 threads.
// f32 in, bf16 out.
__global__ __launch_bounds__(256) void ln_kernel(const float* __restrict__ x,
                                                 const float* __restrict__ g,
                                                 const float* __restrict__ be,
                                                 short* __restrict__ out, int L) {
    long row = blockIdx.x;
    const float* xr = x + row * L;
    short* orow = out + row * L;
    int tid = threadIdx.x;
    int i0 = tid * 4;
    bool active = i0 < L;
    float v0 = 0.f, v1 = 0.f, v2 = 0.f, v3 = 0.f;
    if (active) {
        float4 p = *(const float4*)&xr[i0];
        v0 = p.x; v1 = p.y; v2 = p.z; v3 = p.w;
    }
    float s = v0 + v1 + v2 + v3;
    float s2 = v0*v0 + v1*v1 + v2*v2 + v3*v3;
    #pragma unroll
    for (int off = 32; off > 0; off >>= 1) {
        s  += __shfl_down(s, off);
        s2 += __shfl_down(s2, off);
    }
    __shared__ float ss[4], sq[4];
    int wave = tid >> 6, lane = tid & 63;
    if (lane == 0) { ss[wave] = s; sq[wave] = s2; }
    __syncthreads();
    if (tid == 0) {
        float t1 = ss[0] + ss[1] + ss[2] + ss[3];
        float t2 = sq[0] + sq[1] + sq[2] + sq[3];
        float mu = t1 / (float)L;
        float var = t2 / (float)L - mu * mu;
        ss[0] = mu;
        sq[0] = rsqrtf(var + 1e-5f);
    }
    __syncthreads();
    float mu = ss[0], rs = sq[0];
    if (active) {
        float4 gp = *(const float4*)&g[i0];
        float4 bp = *(const float4*)&be[i0];
        short4 o;
        o.x = f2b((v0 - mu) * rs * gp.x + bp.x);
        o.y = f2b((v1 - mu) * rs * gp.y + bp.y);
        o.z = f2b((v2 - mu) * rs * gp.z + bp.z);
        o.w = f2b((v3 - mu) * rs * gp.w + bp.w);
        *(short4*)&orow[i0] = o;
    }
}

// ---------------------------------------------------------------------------
// q softmax over last axis (rows of 128 f32). 4 rows per block (1 wave each).
__global__ __launch_bounds__(256) void qsoftmax_kernel(const float* __restrict__ q,
                                                       short* __restrict__ out) {
    long row = (long)blockIdx.x * 4 + (threadIdx.x >> 6);
    int lane = threadIdx.x & 63;
    const float* qr = q + row * 128;
    float2 p = *(const float2*)&qr[lane * 2];
    float v0 = p.x, v1 = p.y;
    float m = fmaxf(v0, v1);
    #pragma unroll
    for (int off = 32; off > 0; off >>= 1) m = fmaxf(m, __shfl_xor(m, off));
    float e0 = __expf(v0 - m), e1 = __expf(v1 - m);
    float s = e0 + e1;
    #pragma unroll
    for (int off = 32; off > 0; off >>= 1) s += __shfl_xor(s, off);
    float inv = 1.0f / s;
    short2 o; o.x = f2b(e0 * inv); o.y = f2b(e1 * inv);
    *(short2*)&out[row * 128 + lane * 2] = o;
}

// ---------------------------------------------------------------------------
// Column-softmax stats over n (N=2560), coalesced: one channel per thread.
__global__ __launch_bounds__(256) void kstats1(const short* __restrict__ klog,
                                               const float* __restrict__ cmask,
                                               const float* __restrict__ smask,
                                               float* __restrict__ partM,
                                               float* __restrict__ partS) {
    int c = blockIdx.x * 256 + threadIdx.x;
    int b = blockIdx.y;
    int n0 = blockIdx.z * 256;
    const short* base = klog + (long)b * 2560 * 1024 + c;
    float m = -3.4e38f, s = 0.f;
    for (int k = 0; k < 256; ++k) {
        int n = n0 + k;
        float v = b2f(base[(long)n * 1024]) + pen_of(cmask, smask, b, n);
        float nm = fmaxf(m, v);
        s = s * __expf(m - nm) + __expf(v - nm);
        m = nm;
    }
    long o = ((long)(b * 10 + blockIdx.z)) * 1024 + c;
    partM[o] = m;
    partS[o] = s;
}

__global__ __launch_bounds__(256) void kstats2(const float* __restrict__ partM,
                                               const float* __restrict__ partS,
                                               float* __restrict__ Ms,
                                               float* __restrict__ iSs) {
    int c = blockIdx.x * 256 + threadIdx.x;
    int b = blockIdx.y;
    float M = -3.4e38f;
    #pragma unroll
    for (int k = 0; k < 10; ++k)
        M = fmaxf(M, partM[((long)(b * 10 + k)) * 1024 + c]);
    float S = 0.f;
    #pragma unroll
    for (int k = 0; k < 10; ++k) {
        long o = ((long)(b * 10 + k)) * 1024 + c;
        S += partS[o] * __expf(partM[o] - M);
    }
    Ms[b * 1024 + c] = M;
    iSs[b * 1024 + c] = 1.0f / S;
}

// ---------------------------------------------------------------------------
// 128x128-tile bf16 MFMA B^T GEMM with XOR-swizzled LDS (kills the 16-way
// ds_read_b128 bank conflict of the plain m97 layout; swizzle is applied on
// the global source column since global_load_lds pins LDS dest = lane*16).
// MODE 0 (KV) : dual output. n<1024: OutA = bf16(acc + biasK[n]);
//               n>=1024: OutB = bf16((acc + biasV[n-1024]) * mask[row]).
// MODE 2 (ZT) : z=(b,h); OutA[b][row][h*128+n] = bf16(acc)
// MODE 4 (OUT): f32 OutA = acc + biasK[n], batched over z
template<int MODE>
__global__ __launch_bounds__(256) void gemm_bt(
        const short* __restrict__ A, int lda, long strideA,
        const short* __restrict__ B, int ldb,
        void* __restrict__ OutA, void* __restrict__ OutB,
        int ldo, long strideO,
        int K,
        const float* __restrict__ biasK, const float* __restrict__ biasV,
        const float* __restrict__ mask, long strideMask) {
    __shared__ short As[128 * 64];
    __shared__ short Bs[128 * 64];
    int tid = threadIdx.x;
    int wave = tid >> 6, lane = tid & 63;
    int n0 = blockIdx.x * 128;
    int m0 = blockIdx.y * 128;
    int z = blockIdx.z;

    const short* Ab;
    const short* Bb;
    if (MODE == 2) {
        Ab = A + (z & 7) * 128;             // Wy columns h*128..h*128+127
        Bb = B + (long)z * 16384;           // attnD[z] (128 x 128)
    } else if (MODE == 4) {
        Ab = A + (long)z * strideA;         // qsm[b]
        Bb = B + (long)z * 1048576;         // Zt[b]
    } else {
        Ab = A + (long)z * strideA;
        Bb = B;                             // concatenated weights, shared
    }

    f32x4 acc[4][4];
    #pragma unroll
    for (int i = 0; i < 4; ++i)
        #pragma unroll
        for (int j = 0; j < 4; ++j) {
            f32x4 zz = {0.f, 0.f, 0.f, 0.f};
            acc[i][j] = zz;
        }

    int wm = wave >> 1, wn = wave & 1;
    int r = lane & 15, q = lane >> 4;

    for (int k0 = 0; k0 < K; k0 += 64) {
        __syncthreads();
        #pragma unroll
        for (int it = 0; it < 4; ++it) {
            int cid = it * 256 + tid;          // 16B chunk id 0..1023
            int row = cid >> 3;                // tile row 0..127
            int c8  = cid & 7;                 // chunk within row
            int col = ((c8 ^ (row & 7)) << 3); // swizzled short column
            const short* ga = Ab + (long)(m0 + row) * lda + k0 + col;
            const short* gb = Bb + (long)(n0 + row) * ldb + k0 + col;
            async_cp16(ga, &As[cid * 8]);
            async_cp16(gb, &Bs[cid * 8]);
        }
        __syncthreads();
        #pragma unroll
        for (int kk = 0; kk < 64; kk += 32) {
            s16x8 af[4], bfr[4];
            #pragma unroll
            for (int i = 0; i < 4; ++i) {
                int rowA = wm * 64 + i * 16 + r;
                int rowB = wn * 64 + i * 16 + r;
                int ch = (kk >> 3) + q;        // chunk 0..7
                af[i]  = *(const s16x8*)&As[rowA * 64 + ((ch ^ (rowA & 7)) << 3)];
                bfr[i] = *(const s16x8*)&Bs[rowB * 64 + ((ch ^ (rowB & 7)) << 3)];
            }
            #pragma unroll
            for (int i = 0; i < 4; ++i)
                #pragma unroll
                for (int j = 0; j < 4; ++j)
                    acc[i][j] = __builtin_amdgcn_mfma_f32_16x16x32_bf16(af[i], bfr[j], acc[i][j], 0, 0, 0);
        }
    }

    // Epilogue: C/D layout col = lane&15, row = (lane>>4)*4 + reg  [m89/m91]
    #pragma unroll
    for (int i = 0; i < 4; ++i) {
        int gmb = m0 + wm * 64 + i * 16 + q * 4;
        #pragma unroll
        for (int j = 0; j < 4; ++j) {
            int gn = n0 + wn * 64 + j * 16 + r;
            #pragma unroll
            for (int rg = 0; rg < 4; ++rg) {
                int row = gmb + rg;
                float v = acc[i][j][rg];
                if (MODE == 0) {
                    if (gn < 1024) {
                        ((short*)OutA)[(long)z * strideO + (long)row * ldo + gn] =
                            f2b(v + biasK[gn]);
                    } else {
                        int gv = gn - 1024;
                        float mk = mask[(long)z * strideMask + row];
                        ((short*)OutB)[(long)z * strideO + (long)row * ldo + gv] =
                            f2b((v + biasV[gv]) * mk);
                    }
                } else if (MODE == 2) {
                    ((short*)OutA)[(long)(z >> 3) * 1048576 + (long)row * 1024 +
                                   (z & 7) * 128 + gn] = f2b(v);
                } else {
                    ((float*)OutA)[(long)z * strideO + (long)row * ldo + gn] =
                        v + biasK[gn];
                }
            }
        }
    }
}

// ---------------------------------------------------------------------------
// Split-K fused column-softmax + linear-attention KV partial:
// pbuf[z,ns][l][d] = sum_{n in slice ns} exp(klog+pen-M)[n,d] * v[n,l]  (f32)
__global__ __launch_bounds__(256) void attn_part(const short* __restrict__ klog,
                                                 const short* __restrict__ vbuf,
                                                 const float* __restrict__ cmask,
                                                 const float* __restrict__ smask,
                                                 const float* __restrict__ Ms,
                                                 float* __restrict__ pbuf) {
    __shared__ short kT[128 * 64];
    __shared__ short vT[128 * 64];
    int ns = blockIdx.x;
    int z = blockIdx.y;
    int b = z >> 3, h = z & 7;
    int tid = threadIdx.x;
    int wave = tid >> 6, lane = tid & 63;
    int r = lane & 15, q = lane >> 4;
    int wm = wave >> 1, wn = wave & 1;

    int cg = h * 128 + lane * 2;
    float M0 = Ms[b * 1024 + cg];
    float M1 = Ms[b * 1024 + cg + 1];

    f32x4 acc[4][4];
    #pragma unroll
    for (int i = 0; i < 4; ++i)
        #pragma unroll
        for (int j = 0; j < 4; ++j) {
            f32x4 zz = {0.f, 0.f, 0.f, 0.f};
            acc[i][j] = zz;
        }

    long base = ((long)b * 2560) * 1024 + h * 128;
    int nbase = ns * 320;
    int swz = (lane & 7) << 3;
    for (int n0 = 0; n0 < 320; n0 += 64) {
        __syncthreads();
        #pragma unroll 4
        for (int i = 0; i < 16; ++i) {
            int nl = i * 4 + wave;
            int n = nbase + n0 + nl;
            float pen = pen_of(cmask, smask, b, n);
            long g = base + (long)n * 1024 + lane * 2;
            short2 k2 = *(const short2*)&klog[g];
            short2 v2 = *(const short2*)&vbuf[g];
            float w0 = __expf(b2f(k2.x) + pen - M0);
            float w1 = __expf(b2f(k2.y) + pen - M1);
            int c = lane * 2;
            int sw = nl ^ swz;
            kT[c * 64 + sw] = f2b(w0);
            kT[(c + 1) * 64 + sw] = f2b(w1);
            vT[c * 64 + sw] = v2.x;
            vT[(c + 1) * 64 + sw] = v2.y;
        }
        __syncthreads();
        #pragma unroll
        for (int kk = 0; kk < 64; kk += 32) {
            s16x8 af[4], bfr[4];
            #pragma unroll
            for (int i = 0; i < 4; ++i) {
                int cA = wm * 64 + i * 16 + r;
                int cB = wn * 64 + i * 16 + r;
                af[i]  = *(const s16x8*)&kT[cA * 64 + ((kk + q * 8) ^ (((cA >> 1) & 7) << 3))];
                bfr[i] = *(const s16x8*)&vT[cB * 64 + ((kk + q * 8) ^ (((cB >> 1) & 7) << 3))];
            }
            #pragma unroll
            for (int i = 0; i < 4; ++i)
                #pragma unroll
                for (int j = 0; j < 4; ++j)
                    acc[i][j] = __builtin_amdgcn_mfma_f32_16x16x32_bf16(af[i], bfr[j], acc[i][j], 0, 0, 0);
        }
    }
    float* outp = pbuf + ((long)z * 8 + ns) * 16384;
    #pragma unroll
    for (int i = 0; i < 4; ++i) {
        int d0 = wm * 64 + i * 16 + q * 4;
        #pragma unroll
        for (int j = 0; j < 4; ++j) {
            int l = wn * 64 + j * 16 + r;
            *(f32x4*)&outp[l * 128 + d0] = acc[i][j];
        }
    }
}

// Sum the 8 partials, apply 1/S (per d), emit bf16 attnD[z][d][l] (d-major!).
__global__ __launch_bounds__(256) void reduce_attn(const float* __restrict__ pbuf,
                                                   const float* __restrict__ iSs,
                                                   short* __restrict__ attnD) {
    int idx = blockIdx.x * 256 + threadIdx.x;   // over 64*16384
    int z = idx >> 14, rem = idx & 16383;
    int d = rem & 127, l = rem >> 7;
    int b = z >> 3, h = z & 7;
    const float* p = pbuf + (long)z * 8 * 16384 + rem;
    float s = 0.f;
    #pragma unroll
    for (int ns = 0; ns < 8; ++ns) s += p[ns * 16384];
    attnD[(long)z * 16384 + d * 128 + l] = f2b(s * iSs[b * 1024 + h * 128 + d]);
}

// ---------------------------------------------------------------------------
extern "C" void kernel_launch(void* const* d_in, const int* in_sizes, int n_in,
                              void* d_out, int out_size, void* d_ws, size_t ws_size,
                              hipStream_t stream) {
    const float* query = (const float*)d_in[0];
    const float* x     = (const float*)d_in[1];
    const float* cond  = (const float*)d_in[2];
    const float* smask = (const float*)d_in[3];
    const float* cmask = (const float*)d_in[4];
    const float* gx  = (const float*)d_in[5];
    const float* bx  = (const float*)d_in[6];
    const float* gc  = (const float*)d_in[7];
    const float* bc  = (const float*)d_in[8];
    const float* Wkc = (const float*)d_in[9];
    const float* bkc = (const float*)d_in[10];
    const float* Wvc = (const float*)d_in[11];
    const float* bvc = (const float*)d_in[12];
    const float* Wkx = (const float*)d_in[13];
    const float* bkx = (const float*)d_in[14];
    const float* Wvx = (const float*)d_in[15];
    const float* bvx = (const float*)d_in[16];
    const float* Wy  = (const float*)d_in[17];
    const float* by  = (const float*)d_in[18];

    // Workspace layout (bytes) — identical 'need' to the passing r3/r4 runs.
    size_t o_xn    = 0;                      // 33,554,432 (pbuf alias)
    size_t o_cn    = o_xn    + 33554432;     //  4,194,304
    size_t o_klog  = o_cn    + 4194304;      // 41,943,040 (Zt alias after attn)
    size_t o_vbuf  = o_klog  + 41943040;     // 41,943,040
    size_t o_qsm   = o_vbuf  + 41943040;     // 33,554,432
    size_t o_attnD = o_qsm   + 33554432;     //  2,097,152
    size_t o_partM = o_attnD + 2097152;      //    327,680
    size_t o_partS = o_partM + 327680;       //    327,680
    size_t o_Ms    = o_partS + 327680;       //     32,768
    size_t o_iSs   = o_Ms    + 32768;        //     32,768
    size_t o_wkc   = o_iSs   + 32768;        //  1,048,576  } weights contiguous
    size_t o_wvc   = o_wkc   + 1048576;      //  1,048,576  }
    size_t o_wkx   = o_wvc   + 1048576;      //  2,097,152  }
    size_t o_wvx   = o_wkx   + 2097152;      //  2,097,152  }
    size_t o_wy    = o_wvx   + 2097152;      //  2,097,152  }
    size_t need    = o_wy    + 2097152;      // = 166,395,904
    if (ws_size < need) return;  // clean no-op -> diagnosable absmax failure

    char* w = (char*)d_ws;
    short* xn    = (short*)(w + o_xn);
    short* cn    = (short*)(w + o_cn);
    short* klog  = (short*)(w + o_klog);
    short* vbuf  = (short*)(w + o_vbuf);
    short* qsm   = (short*)(w + o_qsm);
    short* attnD = (short*)(w + o_attnD);
    float* partM = (float*)(w + o_partM);
    float* partS = (float*)(w + o_partS);
    float* Ms    = (float*)(w + o_Ms);
    float* iSs   = (float*)(w + o_iSs);
    short* wkc   = (short*)(w + o_wkc);   // [wkc|wvc] = cat B for cond KV GEMM
    short* wkx   = (short*)(w + o_wkx);   // [wkx|wvx] = cat B for x KV GEMM
    short* wy    = (short*)(w + o_wy);
    float* pbuf  = (float*)xn;            // xn dead after KV GEMMs
    short* Zt    = klog;                  // klog dead after attn_part

    // Weight conversion f32 -> bf16 (single launch; dst region is contiguous)
    cvt_all<<<4096, 256, 0, stream>>>(Wkc, Wvc, Wkx, Wvx, Wy, wkc);

    ln_kernel<<<16384, 256, 0, stream>>>(x, gx, bx, xn, 1024);
    ln_kernel<<<4096, 256, 0, stream>>>(cond, gc, bc, cn, 512);
    qsoftmax_kernel<<<32768, 256, 0, stream>>>(query, qsm);

    // Fused k+v projection, x source: N=2048 (k|v), K=1024, M=2048/b, z=8
    gemm_bt<0><<<dim3(16, 16, 8), 256, 0, stream>>>(
        xn, 1024, 2097152L, wkx, 1024,
        klog + 512 * 1024, vbuf + 512 * 1024, 1024, 2621440L,
        1024, bkx, bvx, smask, 2048L);
    // Fused k+v projection, cond source: N=2048, K=512, M=512/b, z=8
    gemm_bt<0><<<dim3(16, 4, 8), 256, 0, stream>>>(
        cn, 512, 262144L, wkc, 512,
        klog, vbuf, 1024, 2621440L,
        512, bkc, bvc, cmask, 512L);

    kstats1<<<dim3(4, 8, 10), 256, 0, stream>>>(klog, cmask, smask, partM, partS);
    kstats2<<<dim3(4, 8), 256, 0, stream>>>(partM, partS, Ms, iSs);

    // Split-K attention KV (pbuf overwrites xn region — xn dead by now)
    attn_part<<<dim3(8, 64), 256, 0, stream>>>(klog, vbuf, cmask, smask, Ms, pbuf);
    reduce_attn<<<4096, 256, 0, stream>>>(pbuf, iSs, attnD);

    // Zt[b][o][h*128+d] = sum_l Wy[o][h*128+l] * attnD[b,h][d][l]
    gemm_bt<2><<<dim3(1, 8, 64), 256, 0, stream>>>(
        wy, 1024, 0L, attnD, 128,
        Zt, nullptr, 1024, 0L,
        128, nullptr, nullptr, nullptr, 0L);
    // out[b] = qsm[b] @ Zt[b]^T + by   (f32 out)
    gemm_bt<4><<<dim3(8, 16, 8), 256, 0, stream>>>(
        qsm, 1024, 2097152L, Zt, 1024,
        d_out, nullptr, 1024, 2097152L,
        1024, by, nullptr, nullptr, 0L);
}